// Round 8
// baseline (615.347 us; speedup 1.0000x reference)
//
#include <hip/hip_runtime.h>

#define D 128
#define EPSBN 1e-5f
#define PB 800   // padded partial-buffer stride (>= fused block count 782)
#define GROWS 64
#define GBK 64

typedef __attribute__((ext_vector_type(8))) short bf16x8;
typedef __attribute__((ext_vector_type(4))) float f32x4;

static __device__ __forceinline__ unsigned short f2b(float f) {
    unsigned u = __float_as_uint(f);
    unsigned r = u + 0x7FFF + ((u >> 16) & 1);   // RNE
    return (unsigned short)(r >> 16);
}
static __device__ __forceinline__ float b2f_lo(unsigned p) { return __uint_as_float(p << 16); }
static __device__ __forceinline__ float b2f_hi(unsigned p) { return __uint_as_float(p & 0xFFFF0000u); }

// ---------------- setup kernels ----------------

__global__ void k_deg(const int* __restrict__ ei, int E, int* __restrict__ deg,
                      int* __restrict__ pos) {
    int e = blockIdx.x * 256 + threadIdx.x;
    if (e < E) pos[e] = atomicAdd(&deg[ei[E + e]], 1);
}

__global__ void k_bsum(const int* __restrict__ deg, int* __restrict__ bsum, int N) {
    __shared__ int sm[256];
    int t = threadIdx.x, v = blockIdx.x * 256 + t;
    sm[t] = (v < N) ? deg[v] : 0;
    __syncthreads();
    for (int off = 128; off > 0; off >>= 1) {
        if (t < off) sm[t] += sm[t + off];
        __syncthreads();
    }
    if (t == 0) bsum[blockIdx.x] = sm[0];
}

__global__ void k_bscan(const int* __restrict__ bsum, int* __restrict__ boff,
                        int* __restrict__ row_ptr, int NB, int N, int E) {
    __shared__ int sm[256];
    int t = threadIdx.x;
    int v = (t < NB) ? bsum[t] : 0;
    sm[t] = v;
    __syncthreads();
    for (int off = 1; off < 256; off <<= 1) {
        int x = (t >= off) ? sm[t - off] : 0;
        __syncthreads();
        sm[t] += x;
        __syncthreads();
    }
    if (t < NB) boff[t] = sm[t] - v;
    if (t == 0) row_ptr[N] = E;
}

__global__ void k_scatter(const int* __restrict__ deg, const int* __restrict__ boff,
                          int* __restrict__ row_ptr, int N) {
    __shared__ int sm[256];
    int t = threadIdx.x, v = blockIdx.x * 256 + t;
    int val = (v < N) ? deg[v] : 0;
    sm[t] = val;
    __syncthreads();
    for (int off = 1; off < 256; off <<= 1) {
        int x = (t >= off) ? sm[t - off] : 0;
        __syncthreads();
        sm[t] += x;
        __syncthreads();
    }
    if (v < N) row_ptr[v] = boff[blockIdx.x] + sm[t] - val;
}

// atomic-free CSR placement using precomputed ranks
__global__ void k_place(const int* __restrict__ ei, const int* __restrict__ row_ptr,
                        const int* __restrict__ pos, int2* __restrict__ csr, int E) {
    int e = blockIdx.x * 256 + threadIdx.x;
    if (e >= E) return;
    int c = ei[E + e];
    csr[row_ptr[c] + pos[e]] = make_int2(ei[e], e);
}

// cvals[v] = sum nm_e * attr[e]; rewrites csr[j] = (src, nm). dinv inline from deg.
__global__ void k_cvals(const int* __restrict__ row_ptr, int2* __restrict__ csr,
                        const int* __restrict__ deg, const float* __restrict__ attr,
                        float4* __restrict__ cvals, int N) {
    int v = blockIdx.x * 256 + threadIdx.x;
    if (v >= N) return;
    int dgv = deg[v];
    float dv = (dgv > 0) ? rsqrtf((float)dgv) : 0.f;
    int jb = row_ptr[v], je = row_ptr[v + 1];
    float4 acc = make_float4(0.f, 0.f, 0.f, 0.f);
    for (int j = jb; j < je; ++j) {
        int2 e = csr[j];
        int dgs = deg[e.x];
        float ds = (dgs > 0) ? rsqrtf((float)dgs) : 0.f;
        float nm = ds * dv;
        float4 a = *(const float4*)(attr + (size_t)e.y * 4);
        acc.x += nm * a.x; acc.y += nm * a.y;
        acc.z += nm * a.z; acc.w += nm * a.w;
        csr[j] = make_int2(e.x, __float_as_int(nm));
    }
    cvals[v] = acc;
}

__global__ void k_cvt(const float* __restrict__ in, unsigned short* __restrict__ outp, int n4) {
    int i = blockIdx.x * 256 + threadIdx.x;
    if (i >= n4) return;
    float4 v = *(const float4*)(in + (size_t)i * 4);
    ushort4 p;
    p.x = f2b(v.x); p.y = f2b(v.y); p.z = f2b(v.z); p.w = f2b(v.w);
    *(ushort4*)(outp + (size_t)i * 4) = p;
}

// ---------------- per-layer kernels ----------------

// Fused SpMM + GEMM + stats. Block owns 64 nodes:
//   phase A: gather messages (8 edges/iter per wave-quarter scheme), add
//            cvals edge term, deposit agg tile as bf16 in LDS (Ag).
//   phase B: MFMA over [h | Ag] x Wm^T, bias+relu, fp32 h2 store,
//            per-column sum/sumsq partials -> pbuf (non-atomic).
__global__ __launch_bounds__(256) void k_fused(
        const unsigned short* __restrict__ hb, const int* __restrict__ row_ptr,
        const int2* __restrict__ csr, const float4* __restrict__ cvals,
        const float* __restrict__ W1l, const float* __restrict__ W2l,
        const unsigned short* __restrict__ Wmb, const float* __restrict__ bml,
        float* __restrict__ h2, float* __restrict__ pbuf, int N) {
    __shared__ unsigned short Ag[GROWS][D + 8];      // 17.4 KB agg tile (bf16)
    __shared__ unsigned short As[GROWS][GBK + 8];    // 9.2 KB
    __shared__ unsigned short Bs[D][GBK + 8];        // 18.4 KB
    __shared__ float sred[2][4][D];                  // 4 KB
    int tid = threadIdx.x;
    int lane = tid & 63, wave = tid >> 6;
    int n0 = blockIdx.x * GROWS;
    int l15 = lane & 15, q = lane >> 4;
    int qw = q;          // quarter id for gather phase
    int l4 = l15;
    int d0 = l4 * 8;

    // ---- phase A: gather 16 nodes per wave ----
    for (int i = 0; i < 16; ++i) {
        int r = wave * 16 + i;
        int v = n0 + r;
        float a[8];
#pragma unroll
        for (int k = 0; k < 8; ++k) a[k] = 0.f;
        if (v < N) {
            int jb = row_ptr[v], je = row_ptr[v + 1];
            for (int j0 = jb; j0 < je; j0 += 8) {
                int ja = j0 + qw, jc = j0 + 4 + qw;
                bool oa = (ja < je), oc = (jc < je);
                int2 ea = csr[oa ? ja : jb];
                int2 ec = csr[oc ? jc : jb];
                float na = oa ? __int_as_float(ea.y) : 0.f;
                float nc = oc ? __int_as_float(ec.y) : 0.f;
                uint4 pa = *(const uint4*)(hb + (size_t)ea.x * D + d0);
                uint4 pc = *(const uint4*)(hb + (size_t)ec.x * D + d0);
                a[0] += na * b2f_lo(pa.x) + nc * b2f_lo(pc.x);
                a[1] += na * b2f_hi(pa.x) + nc * b2f_hi(pc.x);
                a[2] += na * b2f_lo(pa.y) + nc * b2f_lo(pc.y);
                a[3] += na * b2f_hi(pa.y) + nc * b2f_hi(pc.y);
                a[4] += na * b2f_lo(pa.z) + nc * b2f_lo(pc.z);
                a[5] += na * b2f_hi(pa.z) + nc * b2f_hi(pc.z);
                a[6] += na * b2f_lo(pa.w) + nc * b2f_lo(pc.w);
                a[7] += na * b2f_hi(pa.w) + nc * b2f_hi(pc.w);
            }
#pragma unroll
            for (int k = 0; k < 8; ++k) {
                a[k] += __shfl_xor(a[k], 16);
                a[k] += __shfl_xor(a[k], 32);
            }
            if (qw == 0) {
                float4 c = cvals[v];
                float4 wa0 = *(const float4*)(W1l + d0);
                float4 wa1 = *(const float4*)(W1l + d0 + 4);
                float4 wb0 = *(const float4*)(W1l + D + d0);
                float4 wb1 = *(const float4*)(W1l + D + d0 + 4);
                float4 wc0 = *(const float4*)(W1l + 2 * D + d0);
                float4 wc1 = *(const float4*)(W1l + 2 * D + d0 + 4);
                float4 wd0 = *(const float4*)(W2l + d0);
                float4 wd1 = *(const float4*)(W2l + d0 + 4);
                a[0] += c.x * wa0.x + c.y * wb0.x + c.z * wc0.x + c.w * wd0.x;
                a[1] += c.x * wa0.y + c.y * wb0.y + c.z * wc0.y + c.w * wd0.y;
                a[2] += c.x * wa0.z + c.y * wb0.z + c.z * wc0.z + c.w * wd0.z;
                a[3] += c.x * wa0.w + c.y * wb0.w + c.z * wc0.w + c.w * wd0.w;
                a[4] += c.x * wa1.x + c.y * wb1.x + c.z * wc1.x + c.w * wd1.x;
                a[5] += c.x * wa1.y + c.y * wb1.y + c.z * wc1.y + c.w * wd1.y;
                a[6] += c.x * wa1.z + c.y * wb1.z + c.z * wc1.z + c.w * wd1.z;
                a[7] += c.x * wa1.w + c.y * wb1.w + c.z * wc1.w + c.w * wd1.w;
            }
        }
        if (qw == 0) {
            uint4 o;
            o.x = ((unsigned)f2b(a[1]) << 16) | (unsigned)f2b(a[0]);
            o.y = ((unsigned)f2b(a[3]) << 16) | (unsigned)f2b(a[2]);
            o.z = ((unsigned)f2b(a[5]) << 16) | (unsigned)f2b(a[4]);
            o.w = ((unsigned)f2b(a[7]) << 16) | (unsigned)f2b(a[6]);
            *(uint4*)&Ag[r][d0] = o;
        }
    }

    // ---- phase B: GEMM ----
    f32x4 acc[8];
#pragma unroll
    for (int t = 0; t < 8; ++t) acc[t] = (f32x4){0.f, 0.f, 0.f, 0.f};

    for (int kc = 0; kc < 4; ++kc) {
        int k0 = (kc & 1) * GBK;
        if (kc < 2) {   // stage h tile from global
#pragma unroll
            for (int i = 0; i < 2; ++i) {
                int idx = tid + i * 256;
                int r = idx >> 3, seg = idx & 7;
                uint4 val = make_uint4(0u, 0u, 0u, 0u);
                if (n0 + r < N) val = *(const uint4*)(hb + (size_t)(n0 + r) * D + k0 + seg * 8);
                *(uint4*)&As[r][seg * 8] = val;
            }
        }
#pragma unroll
        for (int i = 0; i < 4; ++i) {
            int idx = tid + i * 256;
            int n = idx >> 3, seg = idx & 7;
            *(uint4*)&Bs[n][seg * 8] =
                *(const uint4*)(Wmb + (size_t)n * 256 + kc * GBK + seg * 8);
        }
        __syncthreads();
#pragma unroll
        for (int s = 0; s < 2; ++s) {
            bf16x8 a;
            if (kc < 2) a = *(const bf16x8*)&As[wave * 16 + l15][s * 32 + q * 8];
            else        a = *(const bf16x8*)&Ag[wave * 16 + l15][(kc - 2) * GBK + s * 32 + q * 8];
#pragma unroll
            for (int t = 0; t < 8; ++t) {
                bf16x8 b = *(const bf16x8*)&Bs[t * 16 + l15][s * 32 + q * 8];
                acc[t] = __builtin_amdgcn_mfma_f32_16x16x32_bf16(a, b, acc[t], 0, 0, 0);
            }
        }
        __syncthreads();
    }

    // epilogue: bias+relu, fp32 h2 store, column partials
    bool full = (n0 + GROWS <= N);
    float ps[8], pq[8];
#pragma unroll
    for (int t = 0; t < 8; ++t) {
        int n = t * 16 + l15;
        float bias = bml[n];
        float s = 0.f, qs = 0.f;
#pragma unroll
        for (int r = 0; r < 4; ++r) {
            int m = n0 + wave * 16 + q * 4 + r;
            float v = fmaxf(acc[t][r] + bias, 0.f);
            if (full || m < N) {
                h2[(size_t)m * D + n] = v;
                s += v; qs += v * v;
            }
        }
        ps[t] = s; pq[t] = qs;
    }
#pragma unroll
    for (int t = 0; t < 8; ++t) {
        ps[t] += __shfl_xor(ps[t], 16); ps[t] += __shfl_xor(ps[t], 32);
        pq[t] += __shfl_xor(pq[t], 16); pq[t] += __shfl_xor(pq[t], 32);
    }
    if (q == 0) {
#pragma unroll
        for (int t = 0; t < 8; ++t) {
            sred[0][wave][t * 16 + l15] = ps[t];
            sred[1][wave][t * 16 + l15] = pq[t];
        }
    }
    __syncthreads();
    if (tid < D) {
        float s = sred[0][0][tid] + sred[0][1][tid] + sred[0][2][tid] + sred[0][3][tid];
        pbuf[(size_t)tid * PB + blockIdx.x] = s;
    } else {
        int n = tid - D;
        float qv = sred[1][0][n] + sred[1][1][n] + sred[1][2][n] + sred[1][3][n];
        pbuf[(size_t)(n + D) * PB + blockIdx.x] = qv;
    }
}

// fold pbuf partials -> scale/shift
__global__ __launch_bounds__(128) void k_reduce(
        const float* __restrict__ pbuf, const float* __restrict__ gam,
        const float* __restrict__ bet, float* __restrict__ scsh, int nb, int N) {
    int n = blockIdx.x;
    int t = threadIdx.x;
    float s = 0.f, qv = 0.f;
    for (int b = t; b < nb; b += 128) {
        s  += pbuf[(size_t)n * PB + b];
        qv += pbuf[(size_t)(n + D) * PB + b];
    }
#pragma unroll
    for (int off = 32; off > 0; off >>= 1) {
        s += __shfl_down(s, off);
        qv += __shfl_down(qv, off);
    }
    __shared__ float aux[4];
    if ((t & 63) == 0) { aux[t >> 6] = s; aux[2 + (t >> 6)] = qv; }
    __syncthreads();
    if (t == 0) {
        float S = aux[0] + aux[1], Q = aux[2] + aux[3];
        float mean = S / (float)N;
        float var = fmaxf(Q / (float)N - mean * mean, 0.f);
        float sc = gam[n] * rsqrtf(var + EPSBN);
        scsh[n] = sc;
        scsh[D + n] = bet[n] - mean * sc;
    }
}

// norm from fp32 h2 (single rounding): hidden -> bf16 + relu, last -> fp32
__global__ void k_norm(const float* __restrict__ h2, const float* __restrict__ scsh,
                       unsigned short* __restrict__ hb_out, float* __restrict__ out_f,
                       int total4, int last) {
    int i = blockIdx.x * 256 + threadIdx.x;
    if (i >= total4) return;
    int base = i * 4;
    int d = base & (D - 1);
    float4 v = *(const float4*)(h2 + base);
    float4 o;
    o.x = scsh[d + 0] * v.x + scsh[D + d + 0];
    o.y = scsh[d + 1] * v.y + scsh[D + d + 1];
    o.z = scsh[d + 2] * v.z + scsh[D + d + 2];
    o.w = scsh[d + 3] * v.w + scsh[D + d + 3];
    if (!last) {
        o.x = fmaxf(o.x, 0.f); o.y = fmaxf(o.y, 0.f);
        o.z = fmaxf(o.z, 0.f); o.w = fmaxf(o.w, 0.f);
        ushort4 p;
        p.x = f2b(o.x); p.y = f2b(o.y); p.z = f2b(o.z); p.w = f2b(o.w);
        *(ushort4*)(hb_out + base) = p;
    } else {
        *(float4*)(out_f + base) = o;
    }
}

// ---------------- host launcher ----------------

extern "C" void kernel_launch(void* const* d_in, const int* in_sizes, int n_in,
                              void* d_out, int out_size, void* d_ws, size_t ws_size,
                              hipStream_t stream) {
    const float* x    = (const float*)d_in[0];
    const int*   ei   = (const int*)d_in[1];
    const float* attr = (const float*)d_in[2];
    const float* W1   = (const float*)d_in[3];
    const float* W2   = (const float*)d_in[4];
    const float* Wm   = (const float*)d_in[5];
    const float* bm   = (const float*)d_in[6];
    const float* gam  = (const float*)d_in[7];
    const float* bet  = (const float*)d_in[8];
    float* out = (float*)d_out;

    const int N = in_sizes[0] / D;
    const int E = in_sizes[1] / 2;
    const int L = in_sizes[3] / (3 * D);
    const int NB = (N + 255) / 256;

    size_t off = 0;
    auto carve = [&](size_t bytes) {
        void* p = (char*)d_ws + off;
        off += (bytes + 255) & ~(size_t)255;
        return p;
    };
    int*            deg     = (int*)carve((size_t)N * 4);
    int*            row_ptr = (int*)carve((size_t)(N + 1) * 4);
    int*            pos     = (int*)carve((size_t)E * 4);
    int*            bsum    = (int*)carve((size_t)NB * 4);
    int*            boff    = (int*)carve((size_t)NB * 4);
    int2*           csr     = (int2*)carve((size_t)(E + 8) * 8);
    float4*         cvals   = (float4*)carve((size_t)N * 16);
    unsigned short* xb      = (unsigned short*)carve((size_t)N * D * 2);
    unsigned short* hb      = (unsigned short*)carve((size_t)N * D * 2);
    unsigned short* Wmb     = (unsigned short*)carve((size_t)L * D * 256 * 2);
    float*          h2      = (float*)carve((size_t)N * D * 4);
    float*          pbuf    = (float*)carve((size_t)2 * D * PB * 4);
    float*          scsh    = (float*)carve((size_t)2 * D * 4);
    (void)ws_size;

    hipMemsetAsync(deg, 0, (size_t)N * 4, stream);

    const int eb = (E + 255) / 256;
    k_deg<<<eb, 256, 0, stream>>>(ei, E, deg, pos);
    k_bsum<<<NB, 256, 0, stream>>>(deg, bsum, N);
    k_bscan<<<1, 256, 0, stream>>>(bsum, boff, row_ptr, NB, N, E);
    k_scatter<<<NB, 256, 0, stream>>>(deg, boff, row_ptr, N);
    k_place<<<eb, 256, 0, stream>>>(ei, row_ptr, pos, csr, E);
    k_cvals<<<NB, 256, 0, stream>>>(row_ptr, csr, deg, attr, cvals, N);

    const int xq = N * D / 4;
    k_cvt<<<(xq + 255) / 256, 256, 0, stream>>>(x, xb, xq);
    const int wq = L * D * 256 / 4;
    k_cvt<<<(wq + 255) / 256, 256, 0, stream>>>(Wm, Wmb, wq);

    const int total4 = N * D / 4;
    const int normb = (total4 + 255) / 256;
    const int nt = (N + GROWS - 1) / GROWS;

    for (int l = 0; l < L; ++l) {
        const unsigned short* in = (l == 0) ? xb : hb;
        const float* W1l = W1 + (size_t)l * 3 * D;
        const float* W2l = W2 + (size_t)l * D;
        const unsigned short* Wml = Wmb + (size_t)l * D * 256;
        const float* bml = bm + (size_t)l * D;
        int last = (l == L - 1) ? 1 : 0;

        k_fused<<<nt, 256, 0, stream>>>(in, row_ptr, csr, cvals, W1l, W2l,
                                        Wml, bml, h2, pbuf, N);
        k_reduce<<<D, 128, 0, stream>>>(pbuf, gam + (size_t)l * D,
                                        bet + (size_t)l * D, scsh, nt, N);
        k_norm<<<normb, 256, 0, stream>>>(h2, scsh, hb, out, total4, last);
    }
}

// Round 9
// 420.544 us; speedup vs baseline: 1.4632x; 1.4632x over previous
//
#include <hip/hip_runtime.h>

#define D 128
#define EPSBN 1e-5f
#define PB 800   // padded partial-buffer stride (>= gemm block count 782)
#define GROWS 64
#define GBK 64

typedef __attribute__((ext_vector_type(8))) short bf16x8;
typedef __attribute__((ext_vector_type(4))) float f32x4;

static __device__ __forceinline__ unsigned short f2b(float f) {
    unsigned u = __float_as_uint(f);
    unsigned r = u + 0x7FFF + ((u >> 16) & 1);   // RNE
    return (unsigned short)(r >> 16);
}
static __device__ __forceinline__ float b2f_lo(unsigned p) { return __uint_as_float(p << 16); }
static __device__ __forceinline__ float b2f_hi(unsigned p) { return __uint_as_float(p & 0xFFFF0000u); }

// fp16 <-> fp32 (RNE) via _Float16
static __device__ __forceinline__ unsigned short f2h(float f) {
    _Float16 h = (_Float16)f;
    unsigned short u;
    __builtin_memcpy(&u, &h, 2);
    return u;
}
static __device__ __forceinline__ float h2f(unsigned short u) {
    _Float16 h;
    __builtin_memcpy(&h, &u, 2);
    return (float)h;
}
static __device__ __forceinline__ float h2f_lo(unsigned p) { return h2f((unsigned short)(p & 0xFFFF)); }
static __device__ __forceinline__ float h2f_hi(unsigned p) { return h2f((unsigned short)(p >> 16)); }

// ---------------- setup kernels ----------------

// degree count; atomic return value = edge's rank within its column
__global__ void k_deg(const int* __restrict__ ei, int E, int* __restrict__ deg,
                      int* __restrict__ pos) {
    int e = blockIdx.x * 256 + threadIdx.x;
    if (e < E) pos[e] = atomicAdd(&deg[ei[E + e]], 1);
}

__global__ void k_bsum(const int* __restrict__ deg, int* __restrict__ bsum, int N) {
    __shared__ int sm[256];
    int t = threadIdx.x, v = blockIdx.x * 256 + t;
    sm[t] = (v < N) ? deg[v] : 0;
    __syncthreads();
    for (int off = 128; off > 0; off >>= 1) {
        if (t < off) sm[t] += sm[t + off];
        __syncthreads();
    }
    if (t == 0) bsum[blockIdx.x] = sm[0];
}

__global__ void k_bscan(const int* __restrict__ bsum, int* __restrict__ boff,
                        int* __restrict__ row_ptr, int NB, int N, int E) {
    __shared__ int sm[256];
    int t = threadIdx.x;
    int v = (t < NB) ? bsum[t] : 0;
    sm[t] = v;
    __syncthreads();
    for (int off = 1; off < 256; off <<= 1) {
        int x = (t >= off) ? sm[t - off] : 0;
        __syncthreads();
        sm[t] += x;
        __syncthreads();
    }
    if (t < NB) boff[t] = sm[t] - v;
    if (t == 0) row_ptr[N] = E;
}

__global__ void k_scatter(const int* __restrict__ deg, const int* __restrict__ boff,
                          int* __restrict__ row_ptr, int N) {
    __shared__ int sm[256];
    int t = threadIdx.x, v = blockIdx.x * 256 + t;
    int val = (v < N) ? deg[v] : 0;
    sm[t] = val;
    __syncthreads();
    for (int off = 1; off < 256; off <<= 1) {
        int x = (t >= off) ? sm[t - off] : 0;
        __syncthreads();
        sm[t] += x;
        __syncthreads();
    }
    if (v < N) row_ptr[v] = boff[blockIdx.x] + sm[t] - val;
}

// atomic-free CSR placement using precomputed ranks
__global__ void k_place(const int* __restrict__ ei, const int* __restrict__ row_ptr,
                        const int* __restrict__ pos, int2* __restrict__ csr, int E) {
    int e = blockIdx.x * 256 + threadIdx.x;
    if (e >= E) return;
    int c = ei[E + e];
    csr[row_ptr[c] + pos[e]] = make_int2(ei[e], e);
}

// cvals[v] = sum nm_e * attr[e]; rewrites csr[j] = (src, nm). rsqrt(deg) inline.
__global__ void k_cvals(const int* __restrict__ row_ptr, int2* __restrict__ csr,
                        const int* __restrict__ deg, const float* __restrict__ attr,
                        float4* __restrict__ cvals, int N) {
    int v = blockIdx.x * 256 + threadIdx.x;
    if (v >= N) return;
    int dgv = deg[v];
    float dv = (dgv > 0) ? rsqrtf((float)dgv) : 0.f;
    int jb = row_ptr[v], je = row_ptr[v + 1];
    float4 acc = make_float4(0.f, 0.f, 0.f, 0.f);
    for (int j = jb; j < je; ++j) {
        int2 e = csr[j];
        int dgs = deg[e.x];
        float ds = (dgs > 0) ? rsqrtf((float)dgs) : 0.f;
        float nm = ds * dv;
        float4 a = *(const float4*)(attr + (size_t)e.y * 4);
        acc.x += nm * a.x; acc.y += nm * a.y;
        acc.z += nm * a.z; acc.w += nm * a.w;
        csr[j] = make_int2(e.x, __float_as_int(nm));
    }
    cvals[v] = acc;
}

// fp32 -> bf16 pack (4 elems / thread)
__global__ void k_cvt(const float* __restrict__ in, unsigned short* __restrict__ outp, int n4) {
    int i = blockIdx.x * 256 + threadIdx.x;
    if (i >= n4) return;
    float4 v = *(const float4*)(in + (size_t)i * 4);
    ushort4 p;
    p.x = f2b(v.x); p.y = f2b(v.y); p.z = f2b(v.z); p.w = f2b(v.w);
    *(ushort4*)(outp + (size_t)i * 4) = p;
}

// ---------------- per-layer kernels ----------------

// wave per node, 8 edges/iter (2 predicated slots x 4 quarters); csr=(src,nm).
// apply=0: hb is bf16 (layer-0 x), direct. apply=1: hb is fp16 PRE-NORM h2;
// h = relu(sc*h2+sh) applied on the fly (fp32 math, no extra rounding).
__global__ __launch_bounds__(256) void k_spmm(
        const unsigned short* __restrict__ hb, const int* __restrict__ row_ptr,
        const int2* __restrict__ csr, const float4* __restrict__ cvals,
        const float* __restrict__ W1l, const float* __restrict__ W2l,
        const float* __restrict__ scsh, int apply,
        unsigned short* __restrict__ aggb, int N) {
    int lane = threadIdx.x & 63;
    int v = blockIdx.x * 4 + (threadIdx.x >> 6);
    if (v >= N) return;
    int qw = lane >> 4;
    int l4 = lane & 15;
    int d0 = l4 * 8;
    int jb = row_ptr[v], je = row_ptr[v + 1];

    float a[8];
#pragma unroll
    for (int i = 0; i < 8; ++i) a[i] = 0.f;

    if (apply) {
        float sc[8], sh[8];
#pragma unroll
        for (int i = 0; i < 8; i += 4) {
            float4 s = *(const float4*)(scsh + d0 + i);
            float4 t = *(const float4*)(scsh + D + d0 + i);
            sc[i] = s.x; sc[i + 1] = s.y; sc[i + 2] = s.z; sc[i + 3] = s.w;
            sh[i] = t.x; sh[i + 1] = t.y; sh[i + 2] = t.z; sh[i + 3] = t.w;
        }
        for (int j0 = jb; j0 < je; j0 += 8) {
            int ja = j0 + qw, jc = j0 + 4 + qw;
            bool oa = (ja < je), oc = (jc < je);
            int2 ea = csr[oa ? ja : jb];
            int2 ec = csr[oc ? jc : jb];
            float na = oa ? __int_as_float(ea.y) : 0.f;
            float nc = oc ? __int_as_float(ec.y) : 0.f;
            uint4 pa = *(const uint4*)(hb + (size_t)ea.x * D + d0);
            uint4 pc = *(const uint4*)(hb + (size_t)ec.x * D + d0);
            float xa[8] = {h2f_lo(pa.x), h2f_hi(pa.x), h2f_lo(pa.y), h2f_hi(pa.y),
                           h2f_lo(pa.z), h2f_hi(pa.z), h2f_lo(pa.w), h2f_hi(pa.w)};
            float xc[8] = {h2f_lo(pc.x), h2f_hi(pc.x), h2f_lo(pc.y), h2f_hi(pc.y),
                           h2f_lo(pc.z), h2f_hi(pc.z), h2f_lo(pc.w), h2f_hi(pc.w)};
#pragma unroll
            for (int i = 0; i < 8; ++i) {
                a[i] += na * fmaxf(sc[i] * xa[i] + sh[i], 0.f);
                a[i] += nc * fmaxf(sc[i] * xc[i] + sh[i], 0.f);
            }
        }
    } else {
        for (int j0 = jb; j0 < je; j0 += 8) {
            int ja = j0 + qw, jc = j0 + 4 + qw;
            bool oa = (ja < je), oc = (jc < je);
            int2 ea = csr[oa ? ja : jb];
            int2 ec = csr[oc ? jc : jb];
            float na = oa ? __int_as_float(ea.y) : 0.f;
            float nc = oc ? __int_as_float(ec.y) : 0.f;
            uint4 pa = *(const uint4*)(hb + (size_t)ea.x * D + d0);
            uint4 pc = *(const uint4*)(hb + (size_t)ec.x * D + d0);
            a[0] += na * b2f_lo(pa.x) + nc * b2f_lo(pc.x);
            a[1] += na * b2f_hi(pa.x) + nc * b2f_hi(pc.x);
            a[2] += na * b2f_lo(pa.y) + nc * b2f_lo(pc.y);
            a[3] += na * b2f_hi(pa.y) + nc * b2f_hi(pc.y);
            a[4] += na * b2f_lo(pa.z) + nc * b2f_lo(pc.z);
            a[5] += na * b2f_hi(pa.z) + nc * b2f_hi(pc.z);
            a[6] += na * b2f_lo(pa.w) + nc * b2f_lo(pc.w);
            a[7] += na * b2f_hi(pa.w) + nc * b2f_hi(pc.w);
        }
    }
#pragma unroll
    for (int i = 0; i < 8; ++i) {
        a[i] += __shfl_xor(a[i], 16);
        a[i] += __shfl_xor(a[i], 32);
    }
    if (qw == 0) {
        float4 c = cvals[v];
        float4 wa0 = *(const float4*)(W1l + d0);
        float4 wa1 = *(const float4*)(W1l + d0 + 4);
        float4 wb0 = *(const float4*)(W1l + D + d0);
        float4 wb1 = *(const float4*)(W1l + D + d0 + 4);
        float4 wc0 = *(const float4*)(W1l + 2 * D + d0);
        float4 wc1 = *(const float4*)(W1l + 2 * D + d0 + 4);
        float4 wd0 = *(const float4*)(W2l + d0);
        float4 wd1 = *(const float4*)(W2l + d0 + 4);
        a[0] += c.x * wa0.x + c.y * wb0.x + c.z * wc0.x + c.w * wd0.x;
        a[1] += c.x * wa0.y + c.y * wb0.y + c.z * wc0.y + c.w * wd0.y;
        a[2] += c.x * wa0.z + c.y * wb0.z + c.z * wc0.z + c.w * wd0.z;
        a[3] += c.x * wa0.w + c.y * wb0.w + c.z * wc0.w + c.w * wd0.w;
        a[4] += c.x * wa1.x + c.y * wb1.x + c.z * wc1.x + c.w * wd1.x;
        a[5] += c.x * wa1.y + c.y * wb1.y + c.z * wc1.y + c.w * wd1.y;
        a[6] += c.x * wa1.z + c.y * wb1.z + c.z * wc1.z + c.w * wd1.z;
        a[7] += c.x * wa1.w + c.y * wb1.w + c.z * wc1.w + c.w * wd1.w;
        uint4 o;
        o.x = ((unsigned)f2b(a[1]) << 16) | (unsigned)f2b(a[0]);
        o.y = ((unsigned)f2b(a[3]) << 16) | (unsigned)f2b(a[2]);
        o.z = ((unsigned)f2b(a[5]) << 16) | (unsigned)f2b(a[4]);
        o.w = ((unsigned)f2b(a[7]) << 16) | (unsigned)f2b(a[6]);
        *(uint4*)(aggb + (size_t)v * D + d0) = o;
    }
}

// h2 = relu([h, agg] @ Wmb^T + bm) via bf16 MFMA.
// A-operand kc=0,1: apply=0 -> bf16 direct; apply=1 -> fp16 pre-norm h2,
// affine+relu in fp32, round once to bf16. Output: fp16 pre-norm h2 (all
// layers) + non-atomic per-column sum/sumsq partials -> pbuf.
__global__ __launch_bounds__(256) void k_gemm(
        const unsigned short* __restrict__ hsrc, const unsigned short* __restrict__ aggb,
        const unsigned short* __restrict__ Wmb, const float* __restrict__ bml,
        const float* __restrict__ scsh, int apply,
        unsigned short* __restrict__ h2h, float* __restrict__ pbuf, int N) {
    __shared__ unsigned short As[GROWS][GBK + 8];
    __shared__ unsigned short Bs[D][GBK + 8];
    __shared__ float sred[2][4][D];
    int tid = threadIdx.x;
    int lane = tid & 63, wave = tid >> 6;
    int n0 = blockIdx.x * GROWS;
    int l15 = lane & 15, q = lane >> 4;
    f32x4 acc[8];
#pragma unroll
    for (int t = 0; t < 8; ++t) acc[t] = (f32x4){0.f, 0.f, 0.f, 0.f};

    for (int kc = 0; kc < 4; ++kc) {
        const unsigned short* src = (kc < 2) ? hsrc : aggb;
        bool aff = (kc < 2) && apply;
        int k0 = (kc & 1) * GBK;
#pragma unroll
        for (int i = 0; i < 2; ++i) {
            int idx = tid + i * 256;
            int r = idx >> 3, seg = idx & 7;
            uint4 val = make_uint4(0u, 0u, 0u, 0u);
            if (n0 + r < N) val = *(const uint4*)(src + (size_t)(n0 + r) * D + k0 + seg * 8);
            if (aff) {
                int db = k0 + seg * 8;
                float4 s0 = *(const float4*)(scsh + db);
                float4 s1 = *(const float4*)(scsh + db + 4);
                float4 t0 = *(const float4*)(scsh + D + db);
                float4 t1 = *(const float4*)(scsh + D + db + 4);
                float e0 = fmaxf(s0.x * h2f_lo(val.x) + t0.x, 0.f);
                float e1 = fmaxf(s0.y * h2f_hi(val.x) + t0.y, 0.f);
                float e2 = fmaxf(s0.z * h2f_lo(val.y) + t0.z, 0.f);
                float e3 = fmaxf(s0.w * h2f_hi(val.y) + t0.w, 0.f);
                float e4 = fmaxf(s1.x * h2f_lo(val.z) + t1.x, 0.f);
                float e5 = fmaxf(s1.y * h2f_hi(val.z) + t1.y, 0.f);
                float e6 = fmaxf(s1.z * h2f_lo(val.w) + t1.z, 0.f);
                float e7 = fmaxf(s1.w * h2f_hi(val.w) + t1.w, 0.f);
                val.x = ((unsigned)f2b(e1) << 16) | (unsigned)f2b(e0);
                val.y = ((unsigned)f2b(e3) << 16) | (unsigned)f2b(e2);
                val.z = ((unsigned)f2b(e5) << 16) | (unsigned)f2b(e4);
                val.w = ((unsigned)f2b(e7) << 16) | (unsigned)f2b(e6);
            }
            *(uint4*)&As[r][seg * 8] = val;
        }
#pragma unroll
        for (int i = 0; i < 4; ++i) {
            int idx = tid + i * 256;
            int n = idx >> 3, seg = idx & 7;
            *(uint4*)&Bs[n][seg * 8] =
                *(const uint4*)(Wmb + (size_t)n * 256 + kc * GBK + seg * 8);
        }
        __syncthreads();
#pragma unroll
        for (int s = 0; s < 2; ++s) {
            bf16x8 a = *(const bf16x8*)&As[wave * 16 + l15][s * 32 + q * 8];
#pragma unroll
            for (int t = 0; t < 8; ++t) {
                bf16x8 b = *(const bf16x8*)&Bs[t * 16 + l15][s * 32 + q * 8];
                acc[t] = __builtin_amdgcn_mfma_f32_16x16x32_bf16(a, b, acc[t], 0, 0, 0);
            }
        }
        __syncthreads();
    }
    bool full = (n0 + GROWS <= N);
    float ps[8], pq[8];
#pragma unroll
    for (int t = 0; t < 8; ++t) {
        int n = t * 16 + l15;
        float bias = bml[n];
        float s = 0.f, qs = 0.f;
#pragma unroll
        for (int r = 0; r < 4; ++r) {
            int m = n0 + wave * 16 + q * 4 + r;
            float v = fmaxf(acc[t][r] + bias, 0.f);
            if (full || m < N) {
                h2h[(size_t)m * D + n] = f2h(v);
                s += v; qs += v * v;
            }
        }
        ps[t] = s; pq[t] = qs;
    }
#pragma unroll
    for (int t = 0; t < 8; ++t) {
        ps[t] += __shfl_xor(ps[t], 16); ps[t] += __shfl_xor(ps[t], 32);
        pq[t] += __shfl_xor(pq[t], 16); pq[t] += __shfl_xor(pq[t], 32);
    }
    if (q == 0) {
#pragma unroll
        for (int t = 0; t < 8; ++t) {
            sred[0][wave][t * 16 + l15] = ps[t];
            sred[1][wave][t * 16 + l15] = pq[t];
        }
    }
    __syncthreads();
    if (tid < D) {
        float s = sred[0][0][tid] + sred[0][1][tid] + sred[0][2][tid] + sred[0][3][tid];
        pbuf[(size_t)tid * PB + blockIdx.x] = s;
    } else {
        int n = tid - D;
        float qv = sred[1][0][n] + sred[1][1][n] + sred[1][2][n] + sred[1][3][n];
        pbuf[(size_t)(n + D) * PB + blockIdx.x] = qv;
    }
}

// fold pbuf partials -> scale/shift
__global__ __launch_bounds__(128) void k_reduce(
        const float* __restrict__ pbuf, const float* __restrict__ gam,
        const float* __restrict__ bet, float* __restrict__ scsh, int nb, int N) {
    int n = blockIdx.x;
    int t = threadIdx.x;
    float s = 0.f, qv = 0.f;
    for (int b = t; b < nb; b += 128) {
        s  += pbuf[(size_t)n * PB + b];
        qv += pbuf[(size_t)(n + D) * PB + b];
    }
#pragma unroll
    for (int off = 32; off > 0; off >>= 1) {
        s += __shfl_down(s, off);
        qv += __shfl_down(qv, off);
    }
    __shared__ float aux[4];
    if ((t & 63) == 0) { aux[t >> 6] = s; aux[2 + (t >> 6)] = qv; }
    __syncthreads();
    if (t == 0) {
        float S = aux[0] + aux[1], Q = aux[2] + aux[3];
        float mean = S / (float)N;
        float var = fmaxf(Q / (float)N - mean * mean, 0.f);
        float sc = gam[n] * rsqrtf(var + EPSBN);
        scsh[n] = sc;
        scsh[D + n] = bet[n] - mean * sc;
    }
}

// final output: out = sc*h2 + sh (fp32, no relu), h2 fp16
__global__ void k_norm_last(const unsigned short* __restrict__ h2h,
                            const float* __restrict__ scsh,
                            float* __restrict__ out_f, int total4) {
    int i = blockIdx.x * 256 + threadIdx.x;
    if (i >= total4) return;
    int base = i * 4;
    int d = base & (D - 1);
    uint2 p = *(const uint2*)(h2h + base);
    float4 o;
    o.x = scsh[d + 0] * h2f_lo(p.x) + scsh[D + d + 0];
    o.y = scsh[d + 1] * h2f_hi(p.x) + scsh[D + d + 1];
    o.z = scsh[d + 2] * h2f_lo(p.y) + scsh[D + d + 2];
    o.w = scsh[d + 3] * h2f_hi(p.y) + scsh[D + d + 3];
    *(float4*)(out_f + base) = o;
}

// ---------------- host launcher ----------------

extern "C" void kernel_launch(void* const* d_in, const int* in_sizes, int n_in,
                              void* d_out, int out_size, void* d_ws, size_t ws_size,
                              hipStream_t stream) {
    const float* x    = (const float*)d_in[0];
    const int*   ei   = (const int*)d_in[1];
    const float* attr = (const float*)d_in[2];
    const float* W1   = (const float*)d_in[3];
    const float* W2   = (const float*)d_in[4];
    const float* Wm   = (const float*)d_in[5];
    const float* bm   = (const float*)d_in[6];
    const float* gam  = (const float*)d_in[7];
    const float* bet  = (const float*)d_in[8];
    float* out = (float*)d_out;

    const int N = in_sizes[0] / D;
    const int E = in_sizes[1] / 2;
    const int L = in_sizes[3] / (3 * D);
    const int NB = (N + 255) / 256;

    size_t off = 0;
    auto carve = [&](size_t bytes) {
        void* p = (char*)d_ws + off;
        off += (bytes + 255) & ~(size_t)255;
        return p;
    };
    int*            deg     = (int*)carve((size_t)N * 4);
    int*            row_ptr = (int*)carve((size_t)(N + 1) * 4);
    int*            pos     = (int*)carve((size_t)E * 4);
    int*            bsum    = (int*)carve((size_t)NB * 4);
    int*            boff    = (int*)carve((size_t)NB * 4);
    int2*           csr     = (int2*)carve((size_t)(E + 8) * 8);
    float4*         cvals   = (float4*)carve((size_t)N * 16);
    unsigned short* xb      = (unsigned short*)carve((size_t)N * D * 2);
    unsigned short* h2h     = (unsigned short*)carve((size_t)N * D * 2);   // fp16 pre-norm h2
    unsigned short* aggb    = (unsigned short*)carve((size_t)N * D * 2);
    unsigned short* Wmb     = (unsigned short*)carve((size_t)L * D * 256 * 2);
    float*          pbuf    = (float*)carve((size_t)2 * D * PB * 4);
    float*          scsh    = (float*)carve((size_t)2 * D * 4);
    (void)ws_size;

    hipMemsetAsync(deg, 0, (size_t)N * 4, stream);

    const int eb = (E + 255) / 256;
    k_deg<<<eb, 256, 0, stream>>>(ei, E, deg, pos);
    k_bsum<<<NB, 256, 0, stream>>>(deg, bsum, N);
    k_bscan<<<1, 256, 0, stream>>>(bsum, boff, row_ptr, NB, N, E);
    k_scatter<<<NB, 256, 0, stream>>>(deg, boff, row_ptr, N);
    k_place<<<eb, 256, 0, stream>>>(ei, row_ptr, pos, csr, E);
    k_cvals<<<NB, 256, 0, stream>>>(row_ptr, csr, deg, attr, cvals, N);

    const int xq = N * D / 4;
    k_cvt<<<(xq + 255) / 256, 256, 0, stream>>>(x, xb, xq);
    const int wq = L * D * 256 / 4;
    k_cvt<<<(wq + 255) / 256, 256, 0, stream>>>(Wm, Wmb, wq);

    const int total4 = N * D / 4;
    const int nt = (N + GROWS - 1) / GROWS;
    const int spmmb = (N + 3) / 4;

    for (int l = 0; l < L; ++l) {
        const unsigned short* in = (l == 0) ? xb : h2h;
        const int apply = (l > 0) ? 1 : 0;
        const float* W1l = W1 + (size_t)l * 3 * D;
        const float* W2l = W2 + (size_t)l * D;
        const unsigned short* Wml = Wmb + (size_t)l * D * 256;
        const float* bml = bm + (size_t)l * D;

        k_spmm<<<spmmb, 256, 0, stream>>>(in, row_ptr, csr, cvals, W1l, W2l,
                                          scsh, apply, aggb, N);
        k_gemm<<<nt, 256, 0, stream>>>(in, aggb, Wml, bml, scsh, apply,
                                       h2h, pbuf, N);
        k_reduce<<<D, 128, 0, stream>>>(pbuf, gam + (size_t)l * D,
                                        bet + (size_t)l * D, scsh, nt, N);
    }
    k_norm_last<<<(total4 + 255) / 256, 256, 0, stream>>>(h2h, scsh, out, total4);
}

// Round 10
// 388.871 us; speedup vs baseline: 1.5824x; 1.0814x over previous
//
#include <hip/hip_runtime.h>

#define D 128
#define EPSBN 1e-5f
#define PB 400   // padded partial-buffer stride (>= gemm block count 391)
#define GROWS 64
#define GBK 64

typedef __attribute__((ext_vector_type(8))) short bf16x8;
typedef __attribute__((ext_vector_type(4))) float f32x4;

static __device__ __forceinline__ unsigned short f2b(float f) {
    unsigned u = __float_as_uint(f);
    unsigned r = u + 0x7FFF + ((u >> 16) & 1);   // RNE
    return (unsigned short)(r >> 16);
}
static __device__ __forceinline__ float b2f_lo(unsigned p) { return __uint_as_float(p << 16); }
static __device__ __forceinline__ float b2f_hi(unsigned p) { return __uint_as_float(p & 0xFFFF0000u); }

// fp16 <-> fp32 (RNE) via _Float16
static __device__ __forceinline__ unsigned short f2h(float f) {
    _Float16 h = (_Float16)f;
    unsigned short u;
    __builtin_memcpy(&u, &h, 2);
    return u;
}
static __device__ __forceinline__ float h2f(unsigned short u) {
    _Float16 h;
    __builtin_memcpy(&h, &u, 2);
    return (float)h;
}
static __device__ __forceinline__ float h2f_lo(unsigned p) { return h2f((unsigned short)(p & 0xFFFF)); }
static __device__ __forceinline__ float h2f_hi(unsigned p) { return h2f((unsigned short)(p >> 16)); }

// ---------------- setup kernels ----------------

__global__ void k_deg(const int* __restrict__ ei, int E, int* __restrict__ deg,
                      int* __restrict__ pos) {
    int e = blockIdx.x * 256 + threadIdx.x;
    if (e < E) pos[e] = atomicAdd(&deg[ei[E + e]], 1);
}

__global__ void k_bsum(const int* __restrict__ deg, int* __restrict__ bsum, int N) {
    __shared__ int sm[256];
    int t = threadIdx.x, v = blockIdx.x * 256 + t;
    sm[t] = (v < N) ? deg[v] : 0;
    __syncthreads();
    for (int off = 128; off > 0; off >>= 1) {
        if (t < off) sm[t] += sm[t + off];
        __syncthreads();
    }
    if (t == 0) bsum[blockIdx.x] = sm[0];
}

__global__ void k_bscan(const int* __restrict__ bsum, int* __restrict__ boff,
                        int* __restrict__ row_ptr, int NB, int N, int E) {
    __shared__ int sm[256];
    int t = threadIdx.x;
    int v = (t < NB) ? bsum[t] : 0;
    sm[t] = v;
    __syncthreads();
    for (int off = 1; off < 256; off <<= 1) {
        int x = (t >= off) ? sm[t - off] : 0;
        __syncthreads();
        sm[t] += x;
        __syncthreads();
    }
    if (t < NB) boff[t] = sm[t] - v;
    if (t == 0) row_ptr[N] = E;
}

__global__ void k_scatter(const int* __restrict__ deg, const int* __restrict__ boff,
                          int* __restrict__ row_ptr, int N) {
    __shared__ int sm[256];
    int t = threadIdx.x, v = blockIdx.x * 256 + t;
    int val = (v < N) ? deg[v] : 0;
    sm[t] = val;
    __syncthreads();
    for (int off = 1; off < 256; off <<= 1) {
        int x = (t >= off) ? sm[t - off] : 0;
        __syncthreads();
        sm[t] += x;
        __syncthreads();
    }
    if (v < N) row_ptr[v] = boff[blockIdx.x] + sm[t] - val;
}

// atomic-free CSR placement using precomputed ranks
__global__ void k_place(const int* __restrict__ ei, const int* __restrict__ row_ptr,
                        const int* __restrict__ pos, int2* __restrict__ csr, int E) {
    int e = blockIdx.x * 256 + threadIdx.x;
    if (e >= E) return;
    int c = ei[E + e];
    csr[row_ptr[c] + pos[e]] = make_int2(ei[e], e);
}

// cvals[v] = sum nm_e * attr[e]; rewrites csr[j] = (src, nm). rsqrt(deg) inline.
__global__ void k_cvals(const int* __restrict__ row_ptr, int2* __restrict__ csr,
                        const int* __restrict__ deg, const float* __restrict__ attr,
                        float4* __restrict__ cvals, int N) {
    int v = blockIdx.x * 256 + threadIdx.x;
    if (v >= N) return;
    int dgv = deg[v];
    float dv = (dgv > 0) ? rsqrtf((float)dgv) : 0.f;
    int jb = row_ptr[v], je = row_ptr[v + 1];
    float4 acc = make_float4(0.f, 0.f, 0.f, 0.f);
    for (int j = jb; j < je; ++j) {
        int2 e = csr[j];
        int dgs = deg[e.x];
        float ds = (dgs > 0) ? rsqrtf((float)dgs) : 0.f;
        float nm = ds * dv;
        float4 a = *(const float4*)(attr + (size_t)e.y * 4);
        acc.x += nm * a.x; acc.y += nm * a.y;
        acc.z += nm * a.z; acc.w += nm * a.w;
        csr[j] = make_int2(e.x, __float_as_int(nm));
    }
    cvals[v] = acc;
}

// fp32 -> bf16 pack (4 elems / thread)
__global__ void k_cvt(const float* __restrict__ in, unsigned short* __restrict__ outp, int n4) {
    int i = blockIdx.x * 256 + threadIdx.x;
    if (i >= n4) return;
    float4 v = *(const float4*)(in + (size_t)i * 4);
    ushort4 p;
    p.x = f2b(v.x); p.y = f2b(v.y); p.z = f2b(v.z); p.w = f2b(v.w);
    *(ushort4*)(outp + (size_t)i * 4) = p;
}

// ---------------- per-layer kernels ----------------

// 2 nodes per wave (32 lanes each): 2 quarters x 2 slots = 4 edges in
// flight per node, 2 independent latency chains per wave. csr=(src,nm).
// apply=0: hb is bf16 x. apply=1: hb is fp16 pre-norm h2; relu(sc*x+sh)
// applied on the fly in fp32.
__global__ __launch_bounds__(256) void k_spmm(
        const unsigned short* __restrict__ hb, const int* __restrict__ row_ptr,
        const int2* __restrict__ csr, const float4* __restrict__ cvals,
        const float* __restrict__ W1l, const float* __restrict__ W2l,
        const float* __restrict__ scsh, int apply,
        unsigned short* __restrict__ aggb, int N) {
    int lane = threadIdx.x & 63;
    int wave = threadIdx.x >> 6;
    int nh = lane >> 5;                 // node half 0/1
    int v = blockIdx.x * 8 + wave * 2 + nh;
    if (v >= N) return;
    int qw = (lane >> 4) & 1;           // quarter within half
    int l4 = lane & 15;
    int d0 = l4 * 8;
    int jb = row_ptr[v], je = row_ptr[v + 1];

    float a[8];
#pragma unroll
    for (int i = 0; i < 8; ++i) a[i] = 0.f;

    if (apply) {
        float sc[8], sh[8];
#pragma unroll
        for (int i = 0; i < 8; i += 4) {
            float4 s = *(const float4*)(scsh + d0 + i);
            float4 t = *(const float4*)(scsh + D + d0 + i);
            sc[i] = s.x; sc[i + 1] = s.y; sc[i + 2] = s.z; sc[i + 3] = s.w;
            sh[i] = t.x; sh[i + 1] = t.y; sh[i + 2] = t.z; sh[i + 3] = t.w;
        }
        for (int j0 = jb; j0 < je; j0 += 4) {
            int ja = j0 + qw, jc = j0 + 2 + qw;
            bool oa = (ja < je), oc = (jc < je);
            int2 ea = csr[oa ? ja : jb];
            int2 ec = csr[oc ? jc : jb];
            float na = oa ? __int_as_float(ea.y) : 0.f;
            float nc = oc ? __int_as_float(ec.y) : 0.f;
            uint4 pa = *(const uint4*)(hb + (size_t)ea.x * D + d0);
            uint4 pc = *(const uint4*)(hb + (size_t)ec.x * D + d0);
            float xa[8] = {h2f_lo(pa.x), h2f_hi(pa.x), h2f_lo(pa.y), h2f_hi(pa.y),
                           h2f_lo(pa.z), h2f_hi(pa.z), h2f_lo(pa.w), h2f_hi(pa.w)};
            float xc[8] = {h2f_lo(pc.x), h2f_hi(pc.x), h2f_lo(pc.y), h2f_hi(pc.y),
                           h2f_lo(pc.z), h2f_hi(pc.z), h2f_lo(pc.w), h2f_hi(pc.w)};
#pragma unroll
            for (int i = 0; i < 8; ++i) {
                a[i] += na * fmaxf(sc[i] * xa[i] + sh[i], 0.f);
                a[i] += nc * fmaxf(sc[i] * xc[i] + sh[i], 0.f);
            }
        }
    } else {
        for (int j0 = jb; j0 < je; j0 += 4) {
            int ja = j0 + qw, jc = j0 + 2 + qw;
            bool oa = (ja < je), oc = (jc < je);
            int2 ea = csr[oa ? ja : jb];
            int2 ec = csr[oc ? jc : jb];
            float na = oa ? __int_as_float(ea.y) : 0.f;
            float nc = oc ? __int_as_float(ec.y) : 0.f;
            uint4 pa = *(const uint4*)(hb + (size_t)ea.x * D + d0);
            uint4 pc = *(const uint4*)(hb + (size_t)ec.x * D + d0);
            a[0] += na * b2f_lo(pa.x) + nc * b2f_lo(pc.x);
            a[1] += na * b2f_hi(pa.x) + nc * b2f_hi(pc.x);
            a[2] += na * b2f_lo(pa.y) + nc * b2f_lo(pc.y);
            a[3] += na * b2f_hi(pa.y) + nc * b2f_hi(pc.y);
            a[4] += na * b2f_lo(pa.z) + nc * b2f_lo(pc.z);
            a[5] += na * b2f_hi(pa.z) + nc * b2f_hi(pc.z);
            a[6] += na * b2f_lo(pa.w) + nc * b2f_lo(pc.w);
            a[7] += na * b2f_hi(pa.w) + nc * b2f_hi(pc.w);
        }
    }
    // fold the 2 quarters within each 32-lane half
#pragma unroll
    for (int i = 0; i < 8; ++i) a[i] += __shfl_xor(a[i], 16);

    if (qw == 0) {
        float4 c = cvals[v];
        float4 wa0 = *(const float4*)(W1l + d0);
        float4 wa1 = *(const float4*)(W1l + d0 + 4);
        float4 wb0 = *(const float4*)(W1l + D + d0);
        float4 wb1 = *(const float4*)(W1l + D + d0 + 4);
        float4 wc0 = *(const float4*)(W1l + 2 * D + d0);
        float4 wc1 = *(const float4*)(W1l + 2 * D + d0 + 4);
        float4 wd0 = *(const float4*)(W2l + d0);
        float4 wd1 = *(const float4*)(W2l + d0 + 4);
        a[0] += c.x * wa0.x + c.y * wb0.x + c.z * wc0.x + c.w * wd0.x;
        a[1] += c.x * wa0.y + c.y * wb0.y + c.z * wc0.y + c.w * wd0.y;
        a[2] += c.x * wa0.z + c.y * wb0.z + c.z * wc0.z + c.w * wd0.z;
        a[3] += c.x * wa0.w + c.y * wb0.w + c.z * wc0.w + c.w * wd0.w;
        a[4] += c.x * wa1.x + c.y * wb1.x + c.z * wc1.x + c.w * wd1.x;
        a[5] += c.x * wa1.y + c.y * wb1.y + c.z * wc1.y + c.w * wd1.y;
        a[6] += c.x * wa1.z + c.y * wb1.z + c.z * wc1.z + c.w * wd1.z;
        a[7] += c.x * wa1.w + c.y * wb1.w + c.z * wc1.w + c.w * wd1.w;
        uint4 o;
        o.x = ((unsigned)f2b(a[1]) << 16) | (unsigned)f2b(a[0]);
        o.y = ((unsigned)f2b(a[3]) << 16) | (unsigned)f2b(a[2]);
        o.z = ((unsigned)f2b(a[5]) << 16) | (unsigned)f2b(a[4]);
        o.w = ((unsigned)f2b(a[7]) << 16) | (unsigned)f2b(a[6]);
        *(uint4*)(aggb + (size_t)v * D + d0) = o;
    }
}

// h2 = relu([h, agg] @ Wmb^T + bm) via bf16 MFMA, 2 row-tiles per block
// (B-chunk staged once, feeds both tiles). A kc=0,1: apply -> fp16 pre-norm
// h2 affine+relu in fp32, one bf16 rounding. Output fp16 pre-norm h2 +
// per-column sum/sumsq partials over both tiles -> pbuf.
__global__ __launch_bounds__(256) void k_gemm(
        const unsigned short* __restrict__ hsrc, const unsigned short* __restrict__ aggb,
        const unsigned short* __restrict__ Wmb, const float* __restrict__ bml,
        const float* __restrict__ scsh, int apply,
        unsigned short* __restrict__ h2h, float* __restrict__ pbuf, int N) {
    __shared__ unsigned short As[2][GROWS][GBK + 8];
    __shared__ unsigned short Bs[D][GBK + 8];
    __shared__ float sred[2][4][D];
    int tid = threadIdx.x;
    int lane = tid & 63, wave = tid >> 6;
    int n0a = blockIdx.x * (2 * GROWS);
    int l15 = lane & 15, q = lane >> 4;
    f32x4 acc[2][8];
#pragma unroll
    for (int t2 = 0; t2 < 2; ++t2)
#pragma unroll
        for (int t = 0; t < 8; ++t) acc[t2][t] = (f32x4){0.f, 0.f, 0.f, 0.f};

    for (int kc = 0; kc < 4; ++kc) {
        const unsigned short* src = (kc < 2) ? hsrc : aggb;
        bool aff = (kc < 2) && apply;
        int k0 = (kc & 1) * GBK;
#pragma unroll
        for (int t2 = 0; t2 < 2; ++t2) {
#pragma unroll
            for (int i = 0; i < 2; ++i) {
                int idx = tid + i * 256;
                int r = idx >> 3, seg = idx & 7;
                int m = n0a + t2 * GROWS + r;
                uint4 val = make_uint4(0u, 0u, 0u, 0u);
                if (m < N) val = *(const uint4*)(src + (size_t)m * D + k0 + seg * 8);
                if (aff) {
                    int db = k0 + seg * 8;
                    float4 s0 = *(const float4*)(scsh + db);
                    float4 s1 = *(const float4*)(scsh + db + 4);
                    float4 t0 = *(const float4*)(scsh + D + db);
                    float4 t1 = *(const float4*)(scsh + D + db + 4);
                    float e0 = fmaxf(s0.x * h2f_lo(val.x) + t0.x, 0.f);
                    float e1 = fmaxf(s0.y * h2f_hi(val.x) + t0.y, 0.f);
                    float e2 = fmaxf(s0.z * h2f_lo(val.y) + t0.z, 0.f);
                    float e3 = fmaxf(s0.w * h2f_hi(val.y) + t0.w, 0.f);
                    float e4 = fmaxf(s1.x * h2f_lo(val.z) + t1.x, 0.f);
                    float e5 = fmaxf(s1.y * h2f_hi(val.z) + t1.y, 0.f);
                    float e6 = fmaxf(s1.z * h2f_lo(val.w) + t1.z, 0.f);
                    float e7 = fmaxf(s1.w * h2f_hi(val.w) + t1.w, 0.f);
                    val.x = ((unsigned)f2b(e1) << 16) | (unsigned)f2b(e0);
                    val.y = ((unsigned)f2b(e3) << 16) | (unsigned)f2b(e2);
                    val.z = ((unsigned)f2b(e5) << 16) | (unsigned)f2b(e4);
                    val.w = ((unsigned)f2b(e7) << 16) | (unsigned)f2b(e6);
                }
                *(uint4*)&As[t2][r][seg * 8] = val;
            }
        }
#pragma unroll
        for (int i = 0; i < 4; ++i) {
            int idx = tid + i * 256;
            int n = idx >> 3, seg = idx & 7;
            *(uint4*)&Bs[n][seg * 8] =
                *(const uint4*)(Wmb + (size_t)n * 256 + kc * GBK + seg * 8);
        }
        __syncthreads();
#pragma unroll
        for (int s = 0; s < 2; ++s) {
            bf16x8 a0 = *(const bf16x8*)&As[0][wave * 16 + l15][s * 32 + q * 8];
            bf16x8 a1 = *(const bf16x8*)&As[1][wave * 16 + l15][s * 32 + q * 8];
#pragma unroll
            for (int t = 0; t < 8; ++t) {
                bf16x8 b = *(const bf16x8*)&Bs[t * 16 + l15][s * 32 + q * 8];
                acc[0][t] = __builtin_amdgcn_mfma_f32_16x16x32_bf16(a0, b, acc[0][t], 0, 0, 0);
                acc[1][t] = __builtin_amdgcn_mfma_f32_16x16x32_bf16(a1, b, acc[1][t], 0, 0, 0);
            }
        }
        __syncthreads();
    }
    float ps[8], pq[8];
#pragma unroll
    for (int t = 0; t < 8; ++t) { ps[t] = 0.f; pq[t] = 0.f; }
#pragma unroll
    for (int t2 = 0; t2 < 2; ++t2) {
        int n0 = n0a + t2 * GROWS;
        bool full = (n0 + GROWS <= N);
#pragma unroll
        for (int t = 0; t < 8; ++t) {
            int n = t * 16 + l15;
            float bias = bml[n];
#pragma unroll
            for (int r = 0; r < 4; ++r) {
                int m = n0 + wave * 16 + q * 4 + r;
                float v = fmaxf(acc[t2][t][r] + bias, 0.f);
                if (full || m < N) {
                    h2h[(size_t)m * D + n] = f2h(v);
                    ps[t] += v; pq[t] += v * v;
                }
            }
        }
    }
#pragma unroll
    for (int t = 0; t < 8; ++t) {
        ps[t] += __shfl_xor(ps[t], 16); ps[t] += __shfl_xor(ps[t], 32);
        pq[t] += __shfl_xor(pq[t], 16); pq[t] += __shfl_xor(pq[t], 32);
    }
    if (q == 0) {
#pragma unroll
        for (int t = 0; t < 8; ++t) {
            sred[0][wave][t * 16 + l15] = ps[t];
            sred[1][wave][t * 16 + l15] = pq[t];
        }
    }
    __syncthreads();
    if (tid < D) {
        float s = sred[0][0][tid] + sred[0][1][tid] + sred[0][2][tid] + sred[0][3][tid];
        pbuf[(size_t)tid * PB + blockIdx.x] = s;
    } else {
        int n = tid - D;
        float qv = sred[1][0][n] + sred[1][1][n] + sred[1][2][n] + sred[1][3][n];
        pbuf[(size_t)(n + D) * PB + blockIdx.x] = qv;
    }
}

// fold pbuf partials -> scale/shift
__global__ __launch_bounds__(128) void k_reduce(
        const float* __restrict__ pbuf, const float* __restrict__ gam,
        const float* __restrict__ bet, float* __restrict__ scsh, int nb, int N) {
    int n = blockIdx.x;
    int t = threadIdx.x;
    float s = 0.f, qv = 0.f;
    for (int b = t; b < nb; b += 128) {
        s  += pbuf[(size_t)n * PB + b];
        qv += pbuf[(size_t)(n + D) * PB + b];
    }
#pragma unroll
    for (int off = 32; off > 0; off >>= 1) {
        s += __shfl_down(s, off);
        qv += __shfl_down(qv, off);
    }
    __shared__ float aux[4];
    if ((t & 63) == 0) { aux[t >> 6] = s; aux[2 + (t >> 6)] = qv; }
    __syncthreads();
    if (t == 0) {
        float S = aux[0] + aux[1], Q = aux[2] + aux[3];
        float mean = S / (float)N;
        float var = fmaxf(Q / (float)N - mean * mean, 0.f);
        float sc = gam[n] * rsqrtf(var + EPSBN);
        scsh[n] = sc;
        scsh[D + n] = bet[n] - mean * sc;
    }
}

// final output: out = sc*h2 + sh (fp32, no relu), h2 fp16
__global__ void k_norm_last(const unsigned short* __restrict__ h2h,
                            const float* __restrict__ scsh,
                            float* __restrict__ out_f, int total4) {
    int i = blockIdx.x * 256 + threadIdx.x;
    if (i >= total4) return;
    int base = i * 4;
    int d = base & (D - 1);
    uint2 p = *(const uint2*)(h2h + base);
    float4 o;
    o.x = scsh[d + 0] * h2f_lo(p.x) + scsh[D + d + 0];
    o.y = scsh[d + 1] * h2f_hi(p.x) + scsh[D + d + 1];
    o.z = scsh[d + 2] * h2f_lo(p.y) + scsh[D + d + 2];
    o.w = scsh[d + 3] * h2f_hi(p.y) + scsh[D + d + 3];
    *(float4*)(out_f + base) = o;
}

// ---------------- host launcher ----------------

extern "C" void kernel_launch(void* const* d_in, const int* in_sizes, int n_in,
                              void* d_out, int out_size, void* d_ws, size_t ws_size,
                              hipStream_t stream) {
    const float* x    = (const float*)d_in[0];
    const int*   ei   = (const int*)d_in[1];
    const float* attr = (const float*)d_in[2];
    const float* W1   = (const float*)d_in[3];
    const float* W2   = (const float*)d_in[4];
    const float* Wm   = (const float*)d_in[5];
    const float* bm   = (const float*)d_in[6];
    const float* gam  = (const float*)d_in[7];
    const float* bet  = (const float*)d_in[8];
    float* out = (float*)d_out;

    const int N = in_sizes[0] / D;
    const int E = in_sizes[1] / 2;
    const int L = in_sizes[3] / (3 * D);
    const int NB = (N + 255) / 256;

    size_t off = 0;
    auto carve = [&](size_t bytes) {
        void* p = (char*)d_ws + off;
        off += (bytes + 255) & ~(size_t)255;
        return p;
    };
    int*            deg     = (int*)carve((size_t)N * 4);
    int*            row_ptr = (int*)carve((size_t)(N + 1) * 4);
    int*            pos     = (int*)carve((size_t)E * 4);
    int*            bsum    = (int*)carve((size_t)NB * 4);
    int*            boff    = (int*)carve((size_t)NB * 4);
    int2*           csr     = (int2*)carve((size_t)(E + 8) * 8);
    float4*         cvals   = (float4*)carve((size_t)N * 16);
    unsigned short* xb      = (unsigned short*)carve((size_t)N * D * 2);
    unsigned short* h2h     = (unsigned short*)carve((size_t)N * D * 2);   // fp16 pre-norm h2
    unsigned short* aggb    = (unsigned short*)carve((size_t)N * D * 2);
    unsigned short* Wmb     = (unsigned short*)carve((size_t)L * D * 256 * 2);
    float*          pbuf    = (float*)carve((size_t)2 * D * PB * 4);
    float*          scsh    = (float*)carve((size_t)2 * D * 4);
    (void)ws_size;

    hipMemsetAsync(deg, 0, (size_t)N * 4, stream);

    const int eb = (E + 255) / 256;
    k_deg<<<eb, 256, 0, stream>>>(ei, E, deg, pos);
    k_bsum<<<NB, 256, 0, stream>>>(deg, bsum, N);
    k_bscan<<<1, 256, 0, stream>>>(bsum, boff, row_ptr, NB, N, E);
    k_scatter<<<NB, 256, 0, stream>>>(deg, boff, row_ptr, N);
    k_place<<<eb, 256, 0, stream>>>(ei, row_ptr, pos, csr, E);
    k_cvals<<<NB, 256, 0, stream>>>(row_ptr, csr, deg, attr, cvals, N);

    const int xq = N * D / 4;
    k_cvt<<<(xq + 255) / 256, 256, 0, stream>>>(x, xb, xq);
    const int wq = L * D * 256 / 4;
    k_cvt<<<(wq + 255) / 256, 256, 0, stream>>>(Wm, Wmb, wq);

    const int total4 = N * D / 4;
    const int gemmb = (N + 2 * GROWS - 1) / (2 * GROWS);   // 391
    const int spmmb = (N + 7) / 8;

    for (int l = 0; l < L; ++l) {
        const unsigned short* in = (l == 0) ? xb : h2h;
        const int apply = (l > 0) ? 1 : 0;
        const float* W1l = W1 + (size_t)l * 3 * D;
        const float* W2l = W2 + (size_t)l * D;
        const unsigned short* Wml = Wmb + (size_t)l * D * 256;
        const float* bml = bm + (size_t)l * D;

        k_spmm<<<spmmb, 256, 0, stream>>>(in, row_ptr, csr, cvals, W1l, W2l,
                                          scsh, apply, aggb, N);
        k_gemm<<<gemmb, 256, 0, stream>>>(in, aggb, Wml, bml, scsh, apply,
                                          h2h, pbuf, N);
        k_reduce<<<D, 128, 0, stream>>>(pbuf, gam + (size_t)l * D,
                                        bet + (size_t)l * D, scsh, gemmb, N);
    }
    k_norm_last<<<(total4 + 255) / 256, 256, 0, stream>>>(h2h, scsh, out, total4);
}